// Round 1
// baseline (329.180 us; speedup 1.0000x reference)
//
#include <hip/hip_runtime.h>
#include <math.h>

// Problem constants (match reference)
#define BB 2048
#define TT 200
#define CC 128
#define PADV (-4294967295.0f)
#define SCALE 0.08838834764831845f   // 1/sqrt(128)
#define INVT (1.0f / 200.0f)

// One block per batch row. 256 threads = 4 waves.
// out[b,c] = sum_t (softmax_w[t] + 1/T) * keys[b,t,c]
__global__ __launch_bounds__(256) void user_attn_kernel(
    const float* __restrict__ uq,    // [B,1,C]
    const float* __restrict__ keys,  // [B,T,C]
    const int*   __restrict__ klen,  // [B,1]
    const float* __restrict__ W,     // [C,C]
    const float* __restrict__ bias,  // [C]
    float*       __restrict__ out)   // [B,1,C]
{
    const int b    = blockIdx.x;
    const int tid  = threadIdx.x;
    const int lane = tid & 63;
    const int wid  = tid >> 6;

    __shared__ float  s_q[CC];      // tanh(uq @ W + b)
    __shared__ float  s_w[TT];      // align -> softmax coeffs
    __shared__ float  s_uq[CC];
    __shared__ float  s_tmp[8];
    __shared__ float2 s_acc[256];

    const float* kb = keys + (size_t)b * TT * CC;

    // ---- step 1: query = tanh(uq @ W + bias), threads 0..127 each own one output channel d
    if (tid < CC) s_uq[tid] = uq[b * CC + tid];
    __syncthreads();
    if (tid < CC) {
        float acc = bias[tid];
        #pragma unroll 8
        for (int c = 0; c < CC; ++c)
            acc = fmaf(s_uq[c], W[c * CC + tid], acc);   // W read coalesced across threads; L2-resident
        s_q[tid] = tanhf(acc);
    }
    __syncthreads();

    const int len = klen[b];

    // ---- step 2: align[t] = (q . keys[t]) * scale, masked
    // each wave owns t = wid, wid+4, ... ; lane holds 2 channels
    const float q0 = s_q[2 * lane];
    const float q1 = s_q[2 * lane + 1];
    for (int t = wid; t < TT; t += 4) {
        const float2 k = *(const float2*)(kb + t * CC + 2 * lane);
        float d = q0 * k.x + q1 * k.y;
        #pragma unroll
        for (int off = 32; off > 0; off >>= 1)
            d += __shfl_xor(d, off, 64);
        if (lane == 0)
            s_w[t] = (t < len) ? d * SCALE : PADV;
    }
    __syncthreads();

    // ---- step 3: softmax over s_w[0..T), then coeff[t] = w[t] + 1/T
    // (all-PAD row => exp(0)=1 everywhere => uniform 1/T, matching jax)
    float v = (tid < TT) ? s_w[tid] : -INFINITY;
    float m = v;
    #pragma unroll
    for (int off = 32; off > 0; off >>= 1)
        m = fmaxf(m, __shfl_xor(m, off, 64));
    if (lane == 0) s_tmp[wid] = m;
    __syncthreads();
    m = fmaxf(fmaxf(s_tmp[0], s_tmp[1]), fmaxf(s_tmp[2], s_tmp[3]));

    float e = (tid < TT) ? expf(v - m) : 0.0f;
    float ssum = e;
    #pragma unroll
    for (int off = 32; off > 0; off >>= 1)
        ssum += __shfl_xor(ssum, off, 64);
    if (lane == 0) s_tmp[4 + wid] = ssum;
    __syncthreads();
    ssum = s_tmp[4] + s_tmp[5] + s_tmp[6] + s_tmp[7];
    if (tid < TT) s_w[tid] = e / ssum + INVT;
    __syncthreads();

    // ---- step 4: out[c] = sum_t coeff[t] * keys[t,c]
    // 4 t-groups (wid) x 64 channel-pairs (lane), float2 coalesced
    const int c2 = lane * 2;
    float2 acc = make_float2(0.0f, 0.0f);
    for (int t = wid; t < TT; t += 4) {
        const float w  = s_w[t];                         // LDS broadcast
        const float2 k = *(const float2*)(kb + t * CC + c2);
        acc.x = fmaf(w, k.x, acc.x);
        acc.y = fmaf(w, k.y, acc.y);
    }
    s_acc[tid] = acc;
    __syncthreads();
    if (tid < 64) {
        float2 r  = s_acc[tid];
        float2 a1 = s_acc[tid + 64];
        float2 a2 = s_acc[tid + 128];
        float2 a3 = s_acc[tid + 192];
        r.x += a1.x + a2.x + a3.x;
        r.y += a1.y + a2.y + a3.y;
        *(float2*)(out + (size_t)b * CC + c2) = r;
    }
}

extern "C" void kernel_launch(void* const* d_in, const int* in_sizes, int n_in,
                              void* d_out, int out_size, void* d_ws, size_t ws_size,
                              hipStream_t stream) {
    const float* uq   = (const float*)d_in[0];  // user_query [B,1,C]
    const float* keys = (const float*)d_in[1];  // keys [B,T,C]
    const int*   klen = (const int*)d_in[2];    // keys_length [B,1]
    const float* W    = (const float*)d_in[3];  // W [C,C]
    const float* bias = (const float*)d_in[4];  // b [C]
    float* out = (float*)d_out;                 // [B,1,C]

    user_attn_kernel<<<BB, 256, 0, stream>>>(uq, keys, klen, W, bias, out);
}

// Round 2
// 306.248 us; speedup vs baseline: 1.0749x; 1.0749x over previous
//
#include <hip/hip_runtime.h>
#include <hip/hip_bf16.h>
#include <math.h>

#define BB 2048
#define TT 200
#define CC 128
#define PADV (-4294967295.0f)
#define SCALE 0.08838834764831845f   // 1/sqrt(128)
#define INVT (1.0f / 200.0f)
#define PITCH 132                    // bf16 elements per LDS row: 264 B, 8B-aligned, breaks pow2 banks

// One block per batch row. 512 threads = 8 waves. LDS ~54.1 KB -> 3 blocks/CU.
__global__ __launch_bounds__(512) void user_attn_kernel(
    const float* __restrict__ uq,    // [B,1,C]
    const float* __restrict__ keys,  // [B,T,C]
    const int*   __restrict__ klen,  // [B,1]
    const float* __restrict__ W,     // [C,C] row-major W[c][d]
    const float* __restrict__ bias,  // [C]
    float*       __restrict__ out)   // [B,1,C]
{
    const int b    = blockIdx.x;
    const int tid  = threadIdx.x;
    const int lane = tid & 63;
    const int wid  = tid >> 6;

    __shared__ unsigned short s_kb16[TT * PITCH]; // 52800 B; aliased pre/post staging
    __shared__ float s_q[CC];                     // tanh(uq@W + b)
    __shared__ float s_w[TT];                     // scores -> softmax coeffs
    __shared__ float s_tmp[16];

    // aliases into s_kb16 (dead outside the main staged phase)
    float*  s_part = (float*)s_kb16;              // [4][128] GEMV partials (pre-staging)
    float*  s_uq   = (float*)s_kb16 + 512;        // [128]    (pre-staging)
    float4* s_red  = (float4*)s_kb16;             // [8][32]  (post weighted-sum loop)

    const float* kb = keys + (size_t)b * TT * CC;

    // ---- phase 0: q = tanh(uq @ W + bias), parallel GEMV over 512 threads
    if (tid < CC) s_uq[tid] = uq[b * CC + tid];
    __syncthreads();
    {
        const int d    = tid & 127;
        const int part = tid >> 7;            // 0..3, 32 c each
        float acc = 0.0f;
        const int c0 = part * 32;
        #pragma unroll 8
        for (int c = 0; c < 32; ++c)
            acc = fmaf(s_uq[c0 + c], W[(c0 + c) * CC + d], acc);
        s_part[part * CC + d] = acc;
    }
    __syncthreads();
    if (tid < CC) {
        float acc = bias[tid] + s_part[tid] + s_part[CC + tid]
                  + s_part[2 * CC + tid] + s_part[3 * CC + tid];
        s_q[tid] = tanhf(acc);
    }
    __syncthreads();

    const int len = klen[b];

    // per-lane query fragment (4 channels)
    const int cl = lane & 31;
    const int c4 = cl * 4;
    const int h  = lane >> 5;                 // half-wave -> which row of the pair
    const float q0 = s_q[c4], q1 = s_q[c4 + 1], q2 = s_q[c4 + 2], q3 = s_q[c4 + 3];

    // ---- phase 1: fused stage (fp32->bf16 into LDS) + scores (fp32)
    // wave processes row-pair p: half0 -> row 2p, half1 -> row 2p+1; 1024B contiguous per wave-load
    for (int p = wid; p < TT / 2; p += 8) {
        const int r = 2 * p + h;
        const float4 k = *(const float4*)(kb + r * CC + c4);
        float d = q0 * k.x + q1 * k.y + q2 * k.z + q3 * k.w;
        #pragma unroll
        for (int off = 1; off < 32; off <<= 1)
            d += __shfl_xor(d, off, 64);      // reduce within 32-lane half
        if (cl == 0)
            s_w[r] = (r < len) ? d * SCALE : PADV;

        __hip_bfloat16 h0 = __float2bfloat16(k.x);
        __hip_bfloat16 h1 = __float2bfloat16(k.y);
        __hip_bfloat16 h2 = __float2bfloat16(k.z);
        __hip_bfloat16 h3 = __float2bfloat16(k.w);
        ushort4 pk;
        pk.x = *(unsigned short*)&h0; pk.y = *(unsigned short*)&h1;
        pk.z = *(unsigned short*)&h2; pk.w = *(unsigned short*)&h3;
        *(ushort4*)(&s_kb16[(size_t)r * PITCH + c4]) = pk;   // (264r + 8cl) % 8 == 0
    }
    __syncthreads();

    // ---- phase 2: softmax over s_w[0..T) -> coeff[t] = softmax[t] + 1/T
    // all-PAD row => uniform 1/T, matching jax
    {
        float v = (tid < TT) ? s_w[tid] : -INFINITY;
        float m = v;
        #pragma unroll
        for (int off = 1; off < 64; off <<= 1)
            m = fmaxf(m, __shfl_xor(m, off, 64));
        if (lane == 0) s_tmp[wid] = m;
        __syncthreads();
        m = s_tmp[0];
        #pragma unroll
        for (int w = 1; w < 8; ++w) m = fmaxf(m, s_tmp[w]);

        float e = (tid < TT) ? expf(v - m) : 0.0f;
        float ssum = e;
        #pragma unroll
        for (int off = 1; off < 64; off <<= 1)
            ssum += __shfl_xor(ssum, off, 64);
        if (lane == 0) s_tmp[8 + wid] = ssum;
        __syncthreads();
        ssum = 0.0f;
        #pragma unroll
        for (int w = 0; w < 8; ++w) ssum += s_tmp[8 + w];
        if (tid < TT) s_w[tid] = e / ssum + INVT;
    }
    __syncthreads();

    // ---- phase 3: out[c] = sum_t coeff[t] * keys_bf16[t][c], from LDS
    float4 acc = make_float4(0.0f, 0.0f, 0.0f, 0.0f);
    for (int p = wid; p < TT / 2; p += 8) {
        const int r = 2 * p + h;
        const float w = s_w[r];
        const ushort4 pk = *(const ushort4*)(&s_kb16[(size_t)r * PITCH + c4]);
        acc.x = fmaf(w, __uint_as_float((unsigned)pk.x << 16), acc.x);
        acc.y = fmaf(w, __uint_as_float((unsigned)pk.y << 16), acc.y);
        acc.z = fmaf(w, __uint_as_float((unsigned)pk.z << 16), acc.z);
        acc.w = fmaf(w, __uint_as_float((unsigned)pk.w << 16), acc.w);
    }
    // combine the two halves (same channels, disjoint t-sets)
    acc.x += __shfl_xor(acc.x, 32, 64);
    acc.y += __shfl_xor(acc.y, 32, 64);
    acc.z += __shfl_xor(acc.z, 32, 64);
    acc.w += __shfl_xor(acc.w, 32, 64);

    __syncthreads();                          // all s_kb16 reads done before aliasing as s_red
    if (cl == lane)                           // lanes 0..31 of each wave
        s_red[wid * 32 + cl] = acc;
    __syncthreads();

    if (tid < 32) {
        float4 r = s_red[tid];
        #pragma unroll
        for (int w = 1; w < 8; ++w) {
            float4 v = s_red[w * 32 + tid];
            r.x += v.x; r.y += v.y; r.z += v.z; r.w += v.w;
        }
        *(float4*)(out + (size_t)b * CC + 4 * tid) = r;
    }
}

extern "C" void kernel_launch(void* const* d_in, const int* in_sizes, int n_in,
                              void* d_out, int out_size, void* d_ws, size_t ws_size,
                              hipStream_t stream) {
    const float* uq   = (const float*)d_in[0];
    const float* keys = (const float*)d_in[1];
    const int*   klen = (const int*)d_in[2];
    const float* W    = (const float*)d_in[3];
    const float* bias = (const float*)d_in[4];
    float* out = (float*)d_out;

    user_attn_kernel<<<BB, 512, 0, stream>>>(uq, keys, klen, W, bias, out);
}